// Round 1
// baseline (1393.121 us; speedup 1.0000x reference)
//
#include <hip/hip_runtime.h>
#include <hip/hip_bf16.h>

// HetGTCN: algebraic reduction — run hops in the 64-dim W2-projected space.
// y_T = relu(x_T@W1_T+b1)@W2  (fused bf16 MFMA), then 3 linear hops on 64-dim
// features with fp32 atomic scatter-add spmm, then out = hP + b2.

typedef __attribute__((ext_vector_type(8))) short bf16x8;   // 8 bf16 (4 VGPRs)
typedef __attribute__((ext_vector_type(4))) float f32x4;

__device__ inline unsigned short f2bf(float f) {
    unsigned u = __builtin_bit_cast(unsigned, f);
    u += 0x7FFFu + ((u >> 16) & 1u);      // RNE
    return (unsigned short)(u >> 16);
}

// ---- pack W1 (256x256) x3 and W2 (256x64) into bf16 MFMA B-fragment order ----
// packed[((ntile*8 + kk)*64 + lane)*8 + j] = W[k][col],
//   col = ntile*16 + (lane&15), k = kk*32 + (lane>>4)*8 + j
__global__ void k_prep(const float* __restrict__ W1P, const float* __restrict__ W1A,
                       const float* __restrict__ W1S, const float* __restrict__ W2f,
                       unsigned short* __restrict__ out) {
    int i = blockIdx.x * 256 + threadIdx.x;
    if (i < 3 * 65536) {
        int m = i >> 16;
        int r = i & 65535;
        int j = r & 7, l = (r >> 3) & 63, kk = (r >> 9) & 7, nt = (r >> 12) & 15;
        int col = nt * 16 + (l & 15);
        int k = kk * 32 + ((l >> 4) << 3) + j;
        const float* s = (m == 0) ? W1P : (m == 1) ? W1A : W1S;
        out[i] = f2bf(s[k * 256 + col]);
    } else if (i < 3 * 65536 + 16384) {
        int r = i - 3 * 65536;
        int j = r & 7, l = (r >> 3) & 63, kk = (r >> 9) & 7, nt = (r >> 12) & 3;
        int col = nt * 16 + (l & 15);
        int k = kk * 32 + ((l >> 4) << 3) + j;
        out[i] = f2bf(W2f[k * 64 + col]);
    }
}

// ---- fused projection: y[r,0:64] = relu(x[r,:]@W1 + b1) @ W2  ----
// block = 256 thr (4 waves), 64 rows per block. LDS tile XOR-swizzled (G4/T2).
__global__ __launch_bounds__(256)
void k_proj(const float* __restrict__ x, const unsigned short* __restrict__ W1pk,
            const float* __restrict__ b1, const unsigned short* __restrict__ W2pk,
            float* __restrict__ y, int nrows) {
    __shared__ unsigned short xs[64 * 256];   // 32 KiB, also reused as hidden tile
    const int r0 = blockIdx.x * 64;
    const int tid = threadIdx.x;
    const int lane = tid & 63;
    const int w = tid >> 6;
    const int l15 = lane & 15, lhi = lane >> 4;

    // stage x (fp32) -> xs (bf16, swizzled). 2048 chunks of 8 elems.
    #pragma unroll
    for (int c = tid; c < 2048; c += 256) {
        int row = c >> 5;
        int col = (c & 31) << 3;
        float4 f0 = make_float4(0, 0, 0, 0), f1 = f0;
        int gr = r0 + row;
        if (gr < nrows) {
            const float4* p = (const float4*)(x + (size_t)gr * 256 + col);
            f0 = p[0]; f1 = p[1];
        }
        bf16x8 v;
        v[0] = (short)f2bf(f0.x); v[1] = (short)f2bf(f0.y);
        v[2] = (short)f2bf(f0.z); v[3] = (short)f2bf(f0.w);
        v[4] = (short)f2bf(f1.x); v[5] = (short)f2bf(f1.y);
        v[6] = (short)f2bf(f1.z); v[7] = (short)f2bf(f1.w);
        int byte = row * 512 + ((col * 2) ^ ((row & 7) << 4));
        *(bf16x8*)((char*)xs + byte) = v;
    }
    __syncthreads();

    // GEMM1: [64x256] @ W1 -> wave w owns hidden cols [w*64, w*64+64)
    f32x4 acc[4][4] = {};
    #pragma unroll
    for (int kk = 0; kk < 8; ++kk) {
        int k = kk * 32 + lhi * 8;
        bf16x8 a[4], b[4];
        #pragma unroll
        for (int m = 0; m < 4; ++m) {
            int row = m * 16 + l15;
            int byte = row * 512 + ((k * 2) ^ ((row & 7) << 4));
            a[m] = *(const bf16x8*)((const char*)xs + byte);
        }
        #pragma unroll
        for (int n = 0; n < 4; ++n)
            b[n] = *(const bf16x8*)(W1pk + ((((w * 4 + n) * 8 + kk) * 64 + lane) << 3));
        #pragma unroll
        for (int m = 0; m < 4; ++m)
            #pragma unroll
            for (int n = 0; n < 4; ++n)
                acc[m][n] = __builtin_amdgcn_mfma_f32_16x16x32_bf16(a[m], b[n], acc[m][n], 0, 0, 0);
    }
    __syncthreads();   // xs reads done; reuse it for hidden tile

    // epilogue1: +b1, relu, bf16, write hidden tile (swizzled)
    #pragma unroll
    for (int n = 0; n < 4; ++n) {
        int col = w * 64 + n * 16 + l15;
        float bias = b1[col];
        #pragma unroll
        for (int m = 0; m < 4; ++m) {
            #pragma unroll
            for (int q = 0; q < 4; ++q) {
                int row = m * 16 + lhi * 4 + q;
                float v = acc[m][n][q] + bias;
                v = v > 0.f ? v : 0.f;
                int byte = row * 512 + ((col * 2) ^ ((row & 7) << 4));
                *(unsigned short*)((char*)xs + byte) = f2bf(v);
            }
        }
    }
    __syncthreads();

    // GEMM2: hidden[64x256] @ W2 -> [64x64]; wave w owns rows [w*16, w*16+16)
    f32x4 acc2[4] = {};
    #pragma unroll
    for (int kk = 0; kk < 8; ++kk) {
        int k = kk * 32 + lhi * 8;
        int row = w * 16 + l15;
        int byte = row * 512 + ((k * 2) ^ ((row & 7) << 4));
        bf16x8 a = *(const bf16x8*)((const char*)xs + byte);
        #pragma unroll
        for (int n = 0; n < 4; ++n) {
            bf16x8 b = *(const bf16x8*)(W2pk + (((n * 8 + kk) * 64 + lane) << 3));
            acc2[n] = __builtin_amdgcn_mfma_f32_16x16x32_bf16(a, b, acc2[n], 0, 0, 0);
        }
    }
    #pragma unroll
    for (int n = 0; n < 4; ++n) {
        #pragma unroll
        for (int q = 0; q < 4; ++q) {
            int row = w * 16 + lhi * 4 + q;
            int gr = r0 + row;
            if (gr < nrows) y[(size_t)gr * 64 + (n * 16 + l15)] = acc2[n][q];
        }
    }
}

// ---- h init: dst[r,f] = alpha*(dA[r]+dB[r]) * y[r,f]  (pass dB=dA, alpha=0.5 for single diag)
__global__ void k_init(float* __restrict__ dst, const float* __restrict__ y,
                       const float* __restrict__ dA, const float* __restrict__ dB,
                       float alpha, int nrows) {
    int i = blockIdx.x * 256 + threadIdx.x;   // float4 index
    if (i < nrows * 16) {
        int row = i >> 4;
        float s = alpha * (dA[row] + dB[row]);
        float4 v = ((const float4*)y)[i];
        v.x *= s; v.y *= s; v.z *= s; v.w *= s;
        ((float4*)dst)[i] = v;
    }
}

// ---- edge-parallel spmm: dst[row] += scale*val * src[col]; one wave per edge, lane=feature
__global__ __launch_bounds__(256)
void k_spmm(float* __restrict__ dst, const float* __restrict__ src,
            const int* __restrict__ rows, const int* __restrict__ cols,
            const float* __restrict__ vals, float scale, int nE) {
    int wid = (blockIdx.x * 256 + threadIdx.x) >> 6;
    int lane = threadIdx.x & 63;
    int e0 = wid * 4;
    #pragma unroll
    for (int t = 0; t < 4; ++t) {
        int e = e0 + t;
        if (e < nE) {
            float v = vals[e] * scale;
            int r = rows[e], c = cols[e];
            unsafeAtomicAdd(dst + (size_t)r * 64 + lane, v * src[(size_t)c * 64 + lane]);
        }
    }
}

// ---- out = hP + b2
__global__ void k_final(float* __restrict__ out, const float* __restrict__ hP,
                        const float* __restrict__ b2, int nP) {
    int i = blockIdx.x * 256 + threadIdx.x;   // float4 index
    if (i < nP * 16) {
        float4 b = ((const float4*)b2)[i & 15];
        float4 v = ((const float4*)hP)[i];
        v.x += b.x; v.y += b.y; v.z += b.z; v.w += b.w;
        ((float4*)out)[i] = v;
    }
}

extern "C" void kernel_launch(void* const* d_in, const int* in_sizes, int n_in,
                              void* d_out, int out_size, void* d_ws, size_t ws_size,
                              hipStream_t stream) {
    const float* x_P = (const float*)d_in[0];
    const float* x_A = (const float*)d_in[1];
    const float* x_S = (const float*)d_in[2];
    const int* pa_row = (const int*)d_in[3];
    const int* pa_col = (const int*)d_in[4];
    const float* pa_val = (const float*)d_in[5];
    const int* ps_row = (const int*)d_in[6];
    const int* ps_col = (const int*)d_in[7];
    const float* ps_val = (const float*)d_in[8];
    const int* ap_row = (const int*)d_in[9];
    const int* ap_col = (const int*)d_in[10];
    const float* ap_val = (const float*)d_in[11];
    const int* sp_row = (const int*)d_in[12];
    const int* sp_col = (const int*)d_in[13];
    const float* sp_val = (const float*)d_in[14];
    const float* diag_PA = (const float*)d_in[15];
    const float* diag_PS = (const float*)d_in[16];
    const float* diag_AP = (const float*)d_in[17];
    const float* diag_SP = (const float*)d_in[18];
    const float* W1_P = (const float*)d_in[19];
    const float* b1_P = (const float*)d_in[20];
    const float* W1_A = (const float*)d_in[21];
    const float* b1_A = (const float*)d_in[22];
    const float* W1_S = (const float*)d_in[23];
    const float* b1_S = (const float*)d_in[24];
    const float* W2  = (const float*)d_in[25];
    const float* b2  = (const float*)d_in[26];

    const int nP = in_sizes[15], nA = in_sizes[17], nS = in_sizes[18];
    const int ePA = in_sizes[3], ePS = in_sizes[6];

    float* ws = (float*)d_ws;
    float* yP = ws;
    float* yA = yP + (size_t)nP * 64;
    float* yS = yA + (size_t)nA * 64;
    float* hP = yS + (size_t)nS * 64;
    float* hA = hP + (size_t)nP * 64;
    float* hS = hA + (size_t)nA * 64;
    unsigned short* Wpk = (unsigned short*)(hS + (size_t)nS * 64);
    unsigned short* W1pk_P = Wpk;
    unsigned short* W1pk_A = Wpk + 65536;
    unsigned short* W1pk_S = Wpk + 2 * 65536;
    unsigned short* W2pk   = Wpk + 3 * 65536;

    k_prep<<<(212992 + 255) / 256, 256, 0, stream>>>(W1_P, W1_A, W1_S, W2, Wpk);
    k_proj<<<(nP + 63) / 64, 256, 0, stream>>>(x_P, W1pk_P, b1_P, W2pk, yP, nP);
    k_proj<<<(nA + 63) / 64, 256, 0, stream>>>(x_A, W1pk_A, b1_A, W2pk, yA, nA);
    k_proj<<<(nS + 63) / 64, 256, 0, stream>>>(x_S, W1pk_S, b1_S, W2pk, yS, nS);

    for (int hop = 0; hop < 3; ++hop) {
        const float* sA = (hop == 0) ? yA : hA;
        const float* sS = (hop == 0) ? yS : hS;
        // hP = 0.5*(dPA+dPS).yP + 0.5*spmm_pa(hA_old) + 0.5*spmm_ps(hS_old)
        k_init<<<(nP * 16 + 255) / 256, 256, 0, stream>>>(hP, yP, diag_PA, diag_PS, 0.5f, nP);
        k_spmm<<<(ePA + 15) / 16, 256, 0, stream>>>(hP, sA, pa_row, pa_col, pa_val, 0.5f, ePA);
        k_spmm<<<(ePS + 15) / 16, 256, 0, stream>>>(hP, sS, ps_row, ps_col, ps_val, 0.5f, ePS);
        // hA = dAP.yA + spmm_ap(hP_new)
        k_init<<<(nA * 16 + 255) / 256, 256, 0, stream>>>(hA, yA, diag_AP, diag_AP, 0.5f, nA);
        k_spmm<<<(ePA + 15) / 16, 256, 0, stream>>>(hA, hP, ap_row, ap_col, ap_val, 1.0f, ePA);
        // hS = dSP.yS + spmm_sp(hP_new)
        k_init<<<(nS * 16 + 255) / 256, 256, 0, stream>>>(hS, yS, diag_SP, diag_SP, 0.5f, nS);
        k_spmm<<<(ePS + 15) / 16, 256, 0, stream>>>(hS, hP, sp_row, sp_col, sp_val, 1.0f, ePS);
    }
    k_final<<<(nP * 16 + 255) / 256, 256, 0, stream>>>((float*)d_out, hP, b2, nP);
}

// Round 2
// 825.167 us; speedup vs baseline: 1.6883x; 1.6883x over previous
//
#include <hip/hip_runtime.h>
#include <hip/hip_bf16.h>

// HetGTCN: hops run in the 64-dim W2-projected space (W2 commutes with the
// linear hop recurrence). Round 2: CSR-based row-parallel spmm (no fp32
// atomics), diag fused, dead hop-3 hA/hS skipped, b2 fused into last hop.

typedef __attribute__((ext_vector_type(8))) short bf16x8;   // 8 bf16 (4 VGPRs)
typedef __attribute__((ext_vector_type(4))) float f32x4;

__device__ inline unsigned short f2bf(float f) {
    unsigned u = __builtin_bit_cast(unsigned, f);
    u += 0x7FFFu + ((u >> 16) & 1u);      // RNE
    return (unsigned short)(u >> 16);
}

// ---- pack W1 (256x256) x3 and W2 (256x64) into bf16 MFMA B-fragment order ----
__global__ void k_prep(const float* __restrict__ W1P, const float* __restrict__ W1A,
                       const float* __restrict__ W1S, const float* __restrict__ W2f,
                       unsigned short* __restrict__ out) {
    int i = blockIdx.x * 256 + threadIdx.x;
    if (i < 3 * 65536) {
        int m = i >> 16;
        int r = i & 65535;
        int j = r & 7, l = (r >> 3) & 63, kk = (r >> 9) & 7, nt = (r >> 12) & 15;
        int col = nt * 16 + (l & 15);
        int k = kk * 32 + ((l >> 4) << 3) + j;
        const float* s = (m == 0) ? W1P : (m == 1) ? W1A : W1S;
        out[i] = f2bf(s[k * 256 + col]);
    } else if (i < 3 * 65536 + 16384) {
        int r = i - 3 * 65536;
        int j = r & 7, l = (r >> 3) & 63, kk = (r >> 9) & 7, nt = (r >> 12) & 3;
        int col = nt * 16 + (l & 15);
        int k = kk * 32 + ((l >> 4) << 3) + j;
        out[i] = f2bf(W2f[k * 64 + col]);
    }
}

// ---- fused projection: y[r,0:64] = relu(x[r,:]@W1 + b1) @ W2  ----
__global__ __launch_bounds__(256)
void k_proj(const float* __restrict__ x, const unsigned short* __restrict__ W1pk,
            const float* __restrict__ b1, const unsigned short* __restrict__ W2pk,
            float* __restrict__ y, int nrows) {
    __shared__ unsigned short xs[64 * 256];   // 32 KiB, reused for hidden tile
    const int r0 = blockIdx.x * 64;
    const int tid = threadIdx.x;
    const int lane = tid & 63;
    const int w = tid >> 6;
    const int l15 = lane & 15, lhi = lane >> 4;

    #pragma unroll
    for (int c = tid; c < 2048; c += 256) {
        int row = c >> 5;
        int col = (c & 31) << 3;
        float4 f0 = make_float4(0, 0, 0, 0), f1 = f0;
        int gr = r0 + row;
        if (gr < nrows) {
            const float4* p = (const float4*)(x + (size_t)gr * 256 + col);
            f0 = p[0]; f1 = p[1];
        }
        bf16x8 v;
        v[0] = (short)f2bf(f0.x); v[1] = (short)f2bf(f0.y);
        v[2] = (short)f2bf(f0.z); v[3] = (short)f2bf(f0.w);
        v[4] = (short)f2bf(f1.x); v[5] = (short)f2bf(f1.y);
        v[6] = (short)f2bf(f1.z); v[7] = (short)f2bf(f1.w);
        int byte = row * 512 + ((col * 2) ^ ((row & 7) << 4));
        *(bf16x8*)((char*)xs + byte) = v;
    }
    __syncthreads();

    f32x4 acc[4][4] = {};
    #pragma unroll
    for (int kk = 0; kk < 8; ++kk) {
        int k = kk * 32 + lhi * 8;
        bf16x8 a[4], b[4];
        #pragma unroll
        for (int m = 0; m < 4; ++m) {
            int row = m * 16 + l15;
            int byte = row * 512 + ((k * 2) ^ ((row & 7) << 4));
            a[m] = *(const bf16x8*)((const char*)xs + byte);
        }
        #pragma unroll
        for (int n = 0; n < 4; ++n)
            b[n] = *(const bf16x8*)(W1pk + ((((w * 4 + n) * 8 + kk) * 64 + lane) << 3));
        #pragma unroll
        for (int m = 0; m < 4; ++m)
            #pragma unroll
            for (int n = 0; n < 4; ++n)
                acc[m][n] = __builtin_amdgcn_mfma_f32_16x16x32_bf16(a[m], b[n], acc[m][n], 0, 0, 0);
    }
    __syncthreads();

    #pragma unroll
    for (int n = 0; n < 4; ++n) {
        int col = w * 64 + n * 16 + l15;
        float bias = b1[col];
        #pragma unroll
        for (int m = 0; m < 4; ++m) {
            #pragma unroll
            for (int q = 0; q < 4; ++q) {
                int row = m * 16 + lhi * 4 + q;
                float v = acc[m][n][q] + bias;
                v = v > 0.f ? v : 0.f;
                int byte = row * 512 + ((col * 2) ^ ((row & 7) << 4));
                *(unsigned short*)((char*)xs + byte) = f2bf(v);
            }
        }
    }
    __syncthreads();

    f32x4 acc2[4] = {};
    #pragma unroll
    for (int kk = 0; kk < 8; ++kk) {
        int k = kk * 32 + lhi * 8;
        int row = w * 16 + l15;
        int byte = row * 512 + ((k * 2) ^ ((row & 7) << 4));
        bf16x8 a = *(const bf16x8*)((const char*)xs + byte);
        #pragma unroll
        for (int n = 0; n < 4; ++n) {
            bf16x8 b = *(const bf16x8*)(W2pk + (((n * 8 + kk) * 64 + lane) << 3));
            acc2[n] = __builtin_amdgcn_mfma_f32_16x16x32_bf16(a, b, acc2[n], 0, 0, 0);
        }
    }
    #pragma unroll
    for (int n = 0; n < 4; ++n) {
        #pragma unroll
        for (int q = 0; q < 4; ++q) {
            int row = w * 16 + lhi * 4 + q;
            int gr = r0 + row;
            if (gr < nrows) y[(size_t)gr * 64 + (n * 16 + l15)] = acc2[n][q];
        }
    }
}

// ======================= CSR build =======================
__global__ void k_count(const int* __restrict__ rows, int* __restrict__ cnt, int nE) {
    int e = blockIdx.x * 256 + threadIdx.x;
    if (e < nE) atomicAdd(&cnt[rows[e]], 1);
}

__global__ __launch_bounds__(256)
void k_scan1(const int* __restrict__ cnt, int* __restrict__ off,
             int* __restrict__ bsum, int n) {
    __shared__ int sh[256];
    int tid = threadIdx.x;
    int base = blockIdx.x * 1024 + tid * 4;
    int c[4];
    #pragma unroll
    for (int j = 0; j < 4; ++j) c[j] = (base + j < n) ? cnt[base + j] : 0;
    int s = c[0] + c[1] + c[2] + c[3];
    sh[tid] = s;
    __syncthreads();
    #pragma unroll
    for (int o = 1; o < 256; o <<= 1) {
        int v = (tid >= o) ? sh[tid - o] : 0;
        __syncthreads();
        sh[tid] += v;
        __syncthreads();
    }
    int run = sh[tid] - s;           // exclusive base for this thread
    #pragma unroll
    for (int j = 0; j < 4; ++j) {
        if (base + j < n) off[base + j] = run;
        run += c[j];
    }
    if (tid == 255) bsum[blockIdx.x] = sh[255];
}

__global__ __launch_bounds__(256)
void k_scan2(int* __restrict__ bsum, int nb) {   // nb <= 256
    __shared__ int sh[256];
    int tid = threadIdx.x;
    int s = (tid < nb) ? bsum[tid] : 0;
    sh[tid] = s;
    __syncthreads();
    #pragma unroll
    for (int o = 1; o < 256; o <<= 1) {
        int v = (tid >= o) ? sh[tid - o] : 0;
        __syncthreads();
        sh[tid] += v;
        __syncthreads();
    }
    if (tid < nb) bsum[tid] = sh[tid] - s;
}

__global__ void k_scan3(int* __restrict__ off, const int* __restrict__ bsum,
                        int* __restrict__ cursor, int n) {
    int i = blockIdx.x * 256 + threadIdx.x;
    if (i < n) {
        int v = off[i] + bsum[i >> 10];
        off[i] = v;
        cursor[i] = v;
    }
}

__global__ void k_scatter(const int* __restrict__ rows, const int* __restrict__ cols,
                          const float* __restrict__ vals, int* __restrict__ cursor,
                          int2* __restrict__ ent, int nE) {
    int e = blockIdx.x * 256 + threadIdx.x;
    if (e < nE) {
        int r = rows[e];
        int p = atomicAdd(&cursor[r], 1);
        ent[p] = make_int2(cols[e], __float_as_int(vals[e]));
    }
}

// ======================= row-parallel spmm (wave per row, lane = feature) =====
__global__ __launch_bounds__(256)
void k_row1(float* __restrict__ dst, const float* __restrict__ y,
            const float* __restrict__ diag, const int* __restrict__ off,
            const int2* __restrict__ ent, const float* __restrict__ src,
            int n, int nE) {
    int r = (blockIdx.x * 256 + threadIdx.x) >> 6;
    int lane = threadIdx.x & 63;
    if (r >= n) return;
    float acc = diag[r] * y[(size_t)r * 64 + lane];
    int s = off[r];
    int t = (r + 1 < n) ? off[r + 1] : nE;
    int e = s;
    for (; e + 1 < t; e += 2) {
        int2 E0 = ent[e], E1 = ent[e + 1];
        float v0 = __int_as_float(E0.y) * src[(size_t)E0.x * 64 + lane];
        float v1 = __int_as_float(E1.y) * src[(size_t)E1.x * 64 + lane];
        acc += v0 + v1;
    }
    if (e < t) {
        int2 E = ent[e];
        acc += __int_as_float(E.y) * src[(size_t)E.x * 64 + lane];
    }
    dst[(size_t)r * 64 + lane] = acc;
}

// hP = 0.5*(dA+dB)*yP + 0.5*spmm_A(srcA) + 0.5*spmm_B(srcB)  [+ b2]
__global__ __launch_bounds__(256)
void k_row2(float* __restrict__ dst, const float* __restrict__ yP,
            const float* __restrict__ dA, const float* __restrict__ dB,
            const int* __restrict__ offA, const int2* __restrict__ entA,
            const float* __restrict__ srcA,
            const int* __restrict__ offB, const int2* __restrict__ entB,
            const float* __restrict__ srcB,
            const float* __restrict__ b2, int n, int nEA, int nEB) {
    int r = (blockIdx.x * 256 + threadIdx.x) >> 6;
    int lane = threadIdx.x & 63;
    if (r >= n) return;
    float acc = 0.5f * (dA[r] + dB[r]) * yP[(size_t)r * 64 + lane];
    {
        int s = offA[r], t = (r + 1 < n) ? offA[r + 1] : nEA;
        int e = s;
        for (; e + 1 < t; e += 2) {
            int2 E0 = entA[e], E1 = entA[e + 1];
            float v0 = __int_as_float(E0.y) * srcA[(size_t)E0.x * 64 + lane];
            float v1 = __int_as_float(E1.y) * srcA[(size_t)E1.x * 64 + lane];
            acc += 0.5f * (v0 + v1);
        }
        if (e < t) {
            int2 E = entA[e];
            acc += 0.5f * __int_as_float(E.y) * srcA[(size_t)E.x * 64 + lane];
        }
    }
    {
        int s = offB[r], t = (r + 1 < n) ? offB[r + 1] : nEB;
        int e = s;
        for (; e + 1 < t; e += 2) {
            int2 E0 = entB[e], E1 = entB[e + 1];
            float v0 = __int_as_float(E0.y) * srcB[(size_t)E0.x * 64 + lane];
            float v1 = __int_as_float(E1.y) * srcB[(size_t)E1.x * 64 + lane];
            acc += 0.5f * (v0 + v1);
        }
        if (e < t) {
            int2 E = entB[e];
            acc += 0.5f * __int_as_float(E.y) * srcB[(size_t)E.x * 64 + lane];
        }
    }
    if (b2) acc += b2[lane];
    dst[(size_t)r * 64 + lane] = acc;
}

// ======================= fallback (atomic) path kernels =======================
__global__ void k_init(float* __restrict__ dst, const float* __restrict__ y,
                       const float* __restrict__ dA, const float* __restrict__ dB,
                       float alpha, int nrows) {
    int i = blockIdx.x * 256 + threadIdx.x;
    if (i < nrows * 16) {
        int row = i >> 4;
        float s = alpha * (dA[row] + dB[row]);
        float4 v = ((const float4*)y)[i];
        v.x *= s; v.y *= s; v.z *= s; v.w *= s;
        ((float4*)dst)[i] = v;
    }
}

__global__ __launch_bounds__(256)
void k_spmm(float* __restrict__ dst, const float* __restrict__ src,
            const int* __restrict__ rows, const int* __restrict__ cols,
            const float* __restrict__ vals, float scale, int nE) {
    int wid = (blockIdx.x * 256 + threadIdx.x) >> 6;
    int lane = threadIdx.x & 63;
    int e0 = wid * 4;
    #pragma unroll
    for (int t = 0; t < 4; ++t) {
        int e = e0 + t;
        if (e < nE) {
            float v = vals[e] * scale;
            int r = rows[e], c = cols[e];
            unsafeAtomicAdd(dst + (size_t)r * 64 + lane, v * src[(size_t)c * 64 + lane]);
        }
    }
}

__global__ void k_final(float* __restrict__ out, const float* __restrict__ hP,
                        const float* __restrict__ b2, int nP) {
    int i = blockIdx.x * 256 + threadIdx.x;
    if (i < nP * 16) {
        float4 b = ((const float4*)b2)[i & 15];
        float4 v = ((const float4*)hP)[i];
        v.x += b.x; v.y += b.y; v.z += b.z; v.w += b.w;
        ((float4*)out)[i] = v;
    }
}

extern "C" void kernel_launch(void* const* d_in, const int* in_sizes, int n_in,
                              void* d_out, int out_size, void* d_ws, size_t ws_size,
                              hipStream_t stream) {
    const float* x_P = (const float*)d_in[0];
    const float* x_A = (const float*)d_in[1];
    const float* x_S = (const float*)d_in[2];
    const int* pa_row = (const int*)d_in[3];
    const int* pa_col = (const int*)d_in[4];
    const float* pa_val = (const float*)d_in[5];
    const int* ps_row = (const int*)d_in[6];
    const int* ps_col = (const int*)d_in[7];
    const float* ps_val = (const float*)d_in[8];
    const int* ap_row = (const int*)d_in[9];
    const int* ap_col = (const int*)d_in[10];
    const float* ap_val = (const float*)d_in[11];
    const int* sp_row = (const int*)d_in[12];
    const int* sp_col = (const int*)d_in[13];
    const float* sp_val = (const float*)d_in[14];
    const float* diag_PA = (const float*)d_in[15];
    const float* diag_PS = (const float*)d_in[16];
    const float* diag_AP = (const float*)d_in[17];
    const float* diag_SP = (const float*)d_in[18];
    const float* W1_P = (const float*)d_in[19];
    const float* b1_P = (const float*)d_in[20];
    const float* W1_A = (const float*)d_in[21];
    const float* b1_A = (const float*)d_in[22];
    const float* W1_S = (const float*)d_in[23];
    const float* b1_S = (const float*)d_in[24];
    const float* W2  = (const float*)d_in[25];
    const float* b2  = (const float*)d_in[26];

    const int nP = in_sizes[15], nA = in_sizes[17], nS = in_sizes[18];
    const int ePA = in_sizes[3], ePS = in_sizes[6];

    // ---- bump allocator over d_ws ----
    char* base = (char*)d_ws;
    size_t cur = 0;
    auto alloc = [&](size_t bytes) -> char* {
        cur = (cur + 255) & ~(size_t)255;
        char* p = base + cur;
        cur += bytes;
        return p;
    };
    float* yP = (float*)alloc((size_t)nP * 64 * 4);
    float* yA = (float*)alloc((size_t)nA * 64 * 4);
    float* yS = (float*)alloc((size_t)nS * 64 * 4);
    float* hP = (float*)alloc((size_t)nP * 64 * 4);
    float* hA = (float*)alloc((size_t)nA * 64 * 4);
    float* hS = (float*)alloc((size_t)nS * 64 * 4);
    unsigned short* Wpk = (unsigned short*)alloc(212992 * 2);
    unsigned short* W1pk_P = Wpk;
    unsigned short* W1pk_A = Wpk + 65536;
    unsigned short* W1pk_S = Wpk + 2 * 65536;
    unsigned short* W2pk   = Wpk + 3 * 65536;

    // CSR region (contiguous cnt block for one memset)
    int* cntPA = (int*)alloc((size_t)(2 * nP + nA + nS) * 4);
    int* cntPS = cntPA + nP;
    int* cntAP = cntPS + nP;
    int* cntSP = cntAP + nA;
    int* offPA = (int*)alloc((size_t)nP * 4);
    int* offPS = (int*)alloc((size_t)nP * 4);
    int* offAP = (int*)alloc((size_t)nA * 4);
    int* offSP = (int*)alloc((size_t)nS * 4);
    int* curPA = (int*)alloc((size_t)nP * 4);
    int* curPS = (int*)alloc((size_t)nP * 4);
    int* curAP = (int*)alloc((size_t)nA * 4);
    int* curSP = (int*)alloc((size_t)nS * 4);
    int2* entPA = (int2*)alloc((size_t)ePA * 8);
    int2* entPS = (int2*)alloc((size_t)ePS * 8);
    int2* entAP = (int2*)alloc((size_t)ePA * 8);
    int2* entSP = (int2*)alloc((size_t)ePS * 8);
    int* bsum = (int*)alloc(1024 * 4);
    const bool use_csr = (cur <= ws_size);

    // ---- projections (always) ----
    k_prep<<<(212992 + 255) / 256, 256, 0, stream>>>(W1_P, W1_A, W1_S, W2, Wpk);
    k_proj<<<(nP + 63) / 64, 256, 0, stream>>>(x_P, W1pk_P, b1_P, W2pk, yP, nP);
    k_proj<<<(nA + 63) / 64, 256, 0, stream>>>(x_A, W1pk_A, b1_A, W2pk, yA, nA);
    k_proj<<<(nS + 63) / 64, 256, 0, stream>>>(x_S, W1pk_S, b1_S, W2pk, yS, nS);

    if (use_csr) {
        // ---- build 4 CSRs ----
        hipMemsetAsync(cntPA, 0, (size_t)(2 * nP + nA + nS) * 4, stream);
        k_count<<<(ePA + 255) / 256, 256, 0, stream>>>(pa_row, cntPA, ePA);
        k_count<<<(ePS + 255) / 256, 256, 0, stream>>>(ps_row, cntPS, ePS);
        k_count<<<(ePA + 255) / 256, 256, 0, stream>>>(ap_row, cntAP, ePA);
        k_count<<<(ePS + 255) / 256, 256, 0, stream>>>(sp_row, cntSP, ePS);

        struct G { const int* cnt; int* off; int* curp; int n; };
        const G gs[4] = {{cntPA, offPA, curPA, nP}, {cntPS, offPS, curPS, nP},
                         {cntAP, offAP, curAP, nA}, {cntSP, offSP, curSP, nS}};
        for (int g = 0; g < 4; ++g) {
            int n = gs[g].n;
            int nb = (n + 1023) / 1024;
            k_scan1<<<nb, 256, 0, stream>>>(gs[g].cnt, gs[g].off, bsum, n);
            k_scan2<<<1, 256, 0, stream>>>(bsum, nb);
            k_scan3<<<(n + 255) / 256, 256, 0, stream>>>(gs[g].off, bsum, gs[g].curp, n);
        }
        k_scatter<<<(ePA + 255) / 256, 256, 0, stream>>>(pa_row, pa_col, pa_val, curPA, entPA, ePA);
        k_scatter<<<(ePS + 255) / 256, 256, 0, stream>>>(ps_row, ps_col, ps_val, curPS, entPS, ePS);
        k_scatter<<<(ePA + 255) / 256, 256, 0, stream>>>(ap_row, ap_col, ap_val, curAP, entAP, ePA);
        k_scatter<<<(ePS + 255) / 256, 256, 0, stream>>>(sp_row, sp_col, sp_val, curSP, entSP, ePS);

        // ---- hops (hop-3 hA/hS are dead -> skipped) ----
        const int gbP = (nP + 3) / 4, gbA = (nA + 3) / 4, gbS = (nS + 3) / 4;
        // hop 1
        k_row2<<<gbP, 256, 0, stream>>>(hP, yP, diag_PA, diag_PS,
                                        offPA, entPA, yA, offPS, entPS, yS,
                                        (const float*)nullptr, nP, ePA, ePS);
        k_row1<<<gbA, 256, 0, stream>>>(hA, yA, diag_AP, offAP, entAP, hP, nA, ePA);
        k_row1<<<gbS, 256, 0, stream>>>(hS, yS, diag_SP, offSP, entSP, hP, nS, ePS);
        // hop 2
        k_row2<<<gbP, 256, 0, stream>>>(hP, yP, diag_PA, diag_PS,
                                        offPA, entPA, hA, offPS, entPS, hS,
                                        (const float*)nullptr, nP, ePA, ePS);
        k_row1<<<gbA, 256, 0, stream>>>(hA, yA, diag_AP, offAP, entAP, hP, nA, ePA);
        k_row1<<<gbS, 256, 0, stream>>>(hS, yS, diag_SP, offSP, entSP, hP, nS, ePS);
        // hop 3: only hP needed; fuse +b2, write straight to d_out
        k_row2<<<gbP, 256, 0, stream>>>((float*)d_out, yP, diag_PA, diag_PS,
                                        offPA, entPA, hA, offPS, entPS, hS,
                                        b2, nP, ePA, ePS);
    } else {
        // ---- fallback: atomic path (round-1, minus dead hop-3 work) ----
        for (int hop = 0; hop < 3; ++hop) {
            const float* sA = (hop == 0) ? yA : hA;
            const float* sS = (hop == 0) ? yS : hS;
            k_init<<<(nP * 16 + 255) / 256, 256, 0, stream>>>(hP, yP, diag_PA, diag_PS, 0.5f, nP);
            k_spmm<<<(ePA + 15) / 16, 256, 0, stream>>>(hP, sA, pa_row, pa_col, pa_val, 0.5f, ePA);
            k_spmm<<<(ePS + 15) / 16, 256, 0, stream>>>(hP, sS, ps_row, ps_col, ps_val, 0.5f, ePS);
            if (hop < 2) {
                k_init<<<(nA * 16 + 255) / 256, 256, 0, stream>>>(hA, yA, diag_AP, diag_AP, 0.5f, nA);
                k_spmm<<<(ePA + 15) / 16, 256, 0, stream>>>(hA, hP, ap_row, ap_col, ap_val, 1.0f, ePA);
                k_init<<<(nS * 16 + 255) / 256, 256, 0, stream>>>(hS, yS, diag_SP, diag_SP, 0.5f, nS);
                k_spmm<<<(ePS + 15) / 16, 256, 0, stream>>>(hS, hP, sp_row, sp_col, sp_val, 1.0f, ePS);
            }
        }
        k_final<<<(nP * 16 + 255) / 256, 256, 0, stream>>>((float*)d_out, hP, b2, nP);
    }
}

// Round 3
// 775.390 us; speedup vs baseline: 1.7967x; 1.0642x over previous
//
#include <hip/hip_runtime.h>
#include <hip/hip_bf16.h>

// HetGTCN: hops in the 64-dim W2-projected space. Round 3:
//  - single persistent pipelined projection kernel (double-buffered LDS, T14)
//  - bf16 storage for y/h (halves spmm gather/write traffic), fp32 accum
//  - fused CSR build (1 count, 1 fused scan, 1 scatter)

typedef __attribute__((ext_vector_type(8))) short bf16x8;   // 8 bf16 (4 VGPRs)
typedef __attribute__((ext_vector_type(4))) float f32x4;

__device__ inline unsigned short f2bf(float f) {
    unsigned u = __builtin_bit_cast(unsigned, f);
    u += 0x7FFFu + ((u >> 16) & 1u);      // RNE
    return (unsigned short)(u >> 16);
}
__device__ inline float bf2f(unsigned short h) {
    unsigned u = ((unsigned)h) << 16;
    return __builtin_bit_cast(float, u);
}

// ---- pack W1 (256x256) x3 and W2 (256x64) into bf16 MFMA B-fragment order ----
__global__ void k_prep(const float* __restrict__ W1P, const float* __restrict__ W1A,
                       const float* __restrict__ W1S, const float* __restrict__ W2f,
                       unsigned short* __restrict__ out) {
    int i = blockIdx.x * 256 + threadIdx.x;
    if (i < 3 * 65536) {
        int m = i >> 16;
        int r = i & 65535;
        int j = r & 7, l = (r >> 3) & 63, kk = (r >> 9) & 7, nt = (r >> 12) & 15;
        int col = nt * 16 + (l & 15);
        int k = kk * 32 + ((l >> 4) << 3) + j;
        const float* s = (m == 0) ? W1P : (m == 1) ? W1A : W1S;
        out[i] = f2bf(s[k * 256 + col]);
    } else if (i < 3 * 65536 + 16384) {
        int r = i - 3 * 65536;
        int j = r & 7, l = (r >> 3) & 63, kk = (r >> 9) & 7, nt = (r >> 12) & 3;
        int col = nt * 16 + (l & 15);
        int k = kk * 32 + ((l >> 4) << 3) + j;
        out[i] = f2bf(W2f[k * 64 + col]);
    }
}

// ---- fused pipelined projection over all three node types ----
// persistent grid; per tile: y[r,0:64] = relu(x[r,:]@W1+b1)@W2, stored bf16.
__global__ __launch_bounds__(256)
void k_proj_all(const float* __restrict__ xP, const float* __restrict__ xA,
                const float* __restrict__ xS, const unsigned short* __restrict__ Wpk,
                const float* __restrict__ b1P, const float* __restrict__ b1A,
                const float* __restrict__ b1S,
                unsigned short* __restrict__ yP, unsigned short* __restrict__ yA,
                unsigned short* __restrict__ yS, int nP, int nA, int nS) {
    __shared__ unsigned short xs[2][64 * 256];   // 2 x 32 KiB
    const int TP = (nP + 63) >> 6, TA = (nA + 63) >> 6, TS = (nS + 63) >> 6;
    const int TT = TP + TA + TS;
    const int tid = threadIdx.x, lane = tid & 63, w = tid >> 6;
    const int l15 = lane & 15, lhi = lane >> 4;
    const unsigned short* W2pk = Wpk + 3 * 65536;

    float4 xr[16];
    int t = blockIdx.x;
    if (t >= TT) return;

    // issue loads for first tile
    {
        const float* x; int r0, nn;
        if (t < TP) { x = xP; r0 = t << 6; nn = nP; }
        else if (t < TP + TA) { x = xA; r0 = (t - TP) << 6; nn = nA; }
        else { x = xS; r0 = (t - TP - TA) << 6; nn = nS; }
        #pragma unroll
        for (int j = 0; j < 8; ++j) {
            int c = tid + j * 256;
            int row = c >> 5, col = (c & 31) << 3;
            int gr = r0 + row;
            float4 z = make_float4(0, 0, 0, 0);
            xr[2 * j] = z; xr[2 * j + 1] = z;
            if (gr < nn) {
                const float4* p = (const float4*)(x + (size_t)gr * 256 + col);
                xr[2 * j] = p[0]; xr[2 * j + 1] = p[1];
            }
        }
    }
    int p = 0;
    while (t < TT) {
        const unsigned short* W1; const float* b1; unsigned short* y; int r0, nn;
        if (t < TP) { r0 = t << 6; nn = nP; W1 = Wpk; b1 = b1P; y = yP; }
        else if (t < TP + TA) { r0 = (t - TP) << 6; nn = nA; W1 = Wpk + 65536; b1 = b1A; y = yA; }
        else { r0 = (t - TP - TA) << 6; nn = nS; W1 = Wpk + 2 * 65536; b1 = b1S; y = yS; }

        // convert + ds_write staged tile into xs[p]
        #pragma unroll
        for (int j = 0; j < 8; ++j) {
            int c = tid + j * 256;
            int row = c >> 5, col = (c & 31) << 3;
            float4 f0 = xr[2 * j], f1 = xr[2 * j + 1];
            bf16x8 v;
            v[0] = (short)f2bf(f0.x); v[1] = (short)f2bf(f0.y);
            v[2] = (short)f2bf(f0.z); v[3] = (short)f2bf(f0.w);
            v[4] = (short)f2bf(f1.x); v[5] = (short)f2bf(f1.y);
            v[6] = (short)f2bf(f1.z); v[7] = (short)f2bf(f1.w);
            int byte = row * 512 + ((col * 2) ^ ((row & 7) << 4));
            *(bf16x8*)((char*)xs[p] + byte) = v;
        }
        // issue loads for next tile (in flight across GEMM1/GEMM2)
        int tn = t + gridDim.x;
        if (tn < TT) {
            const float* x2; int r02, n2;
            if (tn < TP) { x2 = xP; r02 = tn << 6; n2 = nP; }
            else if (tn < TP + TA) { x2 = xA; r02 = (tn - TP) << 6; n2 = nA; }
            else { x2 = xS; r02 = (tn - TP - TA) << 6; n2 = nS; }
            #pragma unroll
            for (int j = 0; j < 8; ++j) {
                int c = tid + j * 256;
                int row = c >> 5, col = (c & 31) << 3;
                int gr = r02 + row;
                float4 z = make_float4(0, 0, 0, 0), a0 = z, a1 = z;
                if (gr < n2) {
                    const float4* q = (const float4*)(x2 + (size_t)gr * 256 + col);
                    a0 = q[0]; a1 = q[1];
                }
                xr[2 * j] = a0; xr[2 * j + 1] = a1;
            }
        }
        __syncthreads();

        // GEMM1: wave w owns hidden cols [w*64, w*64+64)
        f32x4 acc[4][4] = {};
        #pragma unroll
        for (int kk = 0; kk < 8; ++kk) {
            int k = kk * 32 + lhi * 8;
            bf16x8 a[4], b[4];
            #pragma unroll
            for (int m = 0; m < 4; ++m) {
                int row = m * 16 + l15;
                int byte = row * 512 + ((k * 2) ^ ((row & 7) << 4));
                a[m] = *(const bf16x8*)((const char*)xs[p] + byte);
            }
            #pragma unroll
            for (int nq = 0; nq < 4; ++nq)
                b[nq] = *(const bf16x8*)(W1 + ((((w * 4 + nq) * 8 + kk) * 64 + lane) << 3));
            #pragma unroll
            for (int m = 0; m < 4; ++m)
                #pragma unroll
                for (int nq = 0; nq < 4; ++nq)
                    acc[m][nq] = __builtin_amdgcn_mfma_f32_16x16x32_bf16(a[m], b[nq], acc[m][nq], 0, 0, 0);
        }
        __syncthreads();

        // epilogue1: +b1, relu, bf16 hidden tile back into xs[p]
        #pragma unroll
        for (int nq = 0; nq < 4; ++nq) {
            int col = w * 64 + nq * 16 + l15;
            float bias = b1[col];
            #pragma unroll
            for (int m = 0; m < 4; ++m)
                #pragma unroll
                for (int q = 0; q < 4; ++q) {
                    int row = m * 16 + lhi * 4 + q;
                    float vv = acc[m][nq][q] + bias;
                    vv = vv > 0.f ? vv : 0.f;
                    int byte = row * 512 + ((col * 2) ^ ((row & 7) << 4));
                    *(unsigned short*)((char*)xs[p] + byte) = f2bf(vv);
                }
        }
        __syncthreads();

        // GEMM2: wave w owns rows [w*16, w*16+16); store y bf16
        f32x4 acc2[4] = {};
        #pragma unroll
        for (int kk = 0; kk < 8; ++kk) {
            int k = kk * 32 + lhi * 8;
            int row = w * 16 + l15;
            int byte = row * 512 + ((k * 2) ^ ((row & 7) << 4));
            bf16x8 a = *(const bf16x8*)((const char*)xs[p] + byte);
            #pragma unroll
            for (int nq = 0; nq < 4; ++nq) {
                bf16x8 b = *(const bf16x8*)(W2pk + (((nq * 8 + kk) * 64 + lane) << 3));
                acc2[nq] = __builtin_amdgcn_mfma_f32_16x16x32_bf16(a, b, acc2[nq], 0, 0, 0);
            }
        }
        #pragma unroll
        for (int nq = 0; nq < 4; ++nq)
            #pragma unroll
            for (int q = 0; q < 4; ++q) {
                int row = w * 16 + lhi * 4 + q;
                int gr = r0 + row;
                if (gr < nn) y[(size_t)gr * 64 + (nq * 16 + l15)] = f2bf(acc2[nq][q]);
            }
        t = tn; p ^= 1;
    }
}

// ======================= fused CSR build =======================
// concatenated cnt/off layout: [PA: nP][PS: nP][AP: nA][SP: nS]
__global__ void k_count_all(const int* __restrict__ pa, const int* __restrict__ ps,
                            const int* __restrict__ ap, const int* __restrict__ sp,
                            int* __restrict__ cnt, int nP, int nA, int ePA, int ePS) {
    int i = blockIdx.x * 256 + threadIdx.x;
    int r, base;
    if (i < ePA) { r = pa[i]; base = 0; }
    else if (i < ePA + ePS) { r = ps[i - ePA]; base = nP; }
    else if (i < 2 * ePA + ePS) { r = ap[i - ePA - ePS]; base = 2 * nP; }
    else if (i < 2 * ePA + 2 * ePS) { r = sp[i - 2 * ePA - ePS]; base = 2 * nP + nA; }
    else return;
    atomicAdd(&cnt[base + r], 1);
}

__global__ __launch_bounds__(256)
void k_scan1(const int* __restrict__ cnt, int* __restrict__ off,
             int* __restrict__ bsum, int n) {
    __shared__ int sh[256];
    int tid = threadIdx.x;
    int base = blockIdx.x * 1024 + tid * 4;
    int c[4];
    #pragma unroll
    for (int j = 0; j < 4; ++j) c[j] = (base + j < n) ? cnt[base + j] : 0;
    int s = c[0] + c[1] + c[2] + c[3];
    sh[tid] = s;
    __syncthreads();
    #pragma unroll
    for (int o = 1; o < 256; o <<= 1) {
        int v = (tid >= o) ? sh[tid - o] : 0;
        __syncthreads();
        sh[tid] += v;
        __syncthreads();
    }
    int run = sh[tid] - s;
    #pragma unroll
    for (int j = 0; j < 4; ++j) {
        if (base + j < n) off[base + j] = run;
        run += c[j];
    }
    if (tid == 255) bsum[blockIdx.x] = sh[255];
}

__global__ __launch_bounds__(256)
void k_scan2(int* __restrict__ bsum, int nb) {   // nb <= 1024
    __shared__ int sh[256];
    int tid = threadIdx.x;
    int base = tid * 4;
    int v[4];
    #pragma unroll
    for (int j = 0; j < 4; ++j) v[j] = (base + j < nb) ? bsum[base + j] : 0;
    int s = v[0] + v[1] + v[2] + v[3];
    sh[tid] = s;
    __syncthreads();
    #pragma unroll
    for (int o = 1; o < 256; o <<= 1) {
        int x = (tid >= o) ? sh[tid - o] : 0;
        __syncthreads();
        sh[tid] += x;
        __syncthreads();
    }
    int run = sh[tid] - s;
    #pragma unroll
    for (int j = 0; j < 4; ++j) {
        if (base + j < nb) bsum[base + j] = run;
        run += v[j];
    }
}

// finalize: per-graph normalized off (n+1 entries) + cursor init
__global__ void k_scan3(const int* __restrict__ off0, const int* __restrict__ bsum,
                        int* __restrict__ offPA, int* __restrict__ offPS,
                        int* __restrict__ offAP, int* __restrict__ offSP,
                        int* __restrict__ curPA, int* __restrict__ curPS,
                        int* __restrict__ curAP, int* __restrict__ curSP,
                        int nP, int nA, int nS, int ePA, int ePS) {
    int i = blockIdx.x * 256 + threadIdx.x;
    int NC = 2 * nP + nA + nS;
    if (i >= NC) return;
    int v = off0[i] + bsum[i >> 10];
    int g0, loc, ng, nE; int *og, *cg;
    if (i < nP)                { g0 = 0;           loc = i;                ng = nP; nE = ePA; og = offPA; cg = curPA; }
    else if (i < 2 * nP)       { g0 = nP;          loc = i - nP;           ng = nP; nE = ePS; og = offPS; cg = curPS; }
    else if (i < 2 * nP + nA)  { g0 = 2 * nP;      loc = i - 2 * nP;       ng = nA; nE = ePA; og = offAP; cg = curAP; }
    else                       { g0 = 2 * nP + nA; loc = i - 2 * nP - nA;  ng = nS; nE = ePS; og = offSP; cg = curSP; }
    int basev = off0[g0] + bsum[g0 >> 10];
    int rel = v - basev;
    og[loc] = rel; cg[loc] = rel;
    if (loc == 0) og[ng] = nE;
}

__global__ void k_scatter_all(const int* __restrict__ pa_r, const int* __restrict__ pa_c, const float* __restrict__ pa_v,
                              const int* __restrict__ ps_r, const int* __restrict__ ps_c, const float* __restrict__ ps_v,
                              const int* __restrict__ ap_r, const int* __restrict__ ap_c, const float* __restrict__ ap_v,
                              const int* __restrict__ sp_r, const int* __restrict__ sp_c, const float* __restrict__ sp_v,
                              int* __restrict__ curPA, int* __restrict__ curPS,
                              int* __restrict__ curAP, int* __restrict__ curSP,
                              int2* __restrict__ entPA, int2* __restrict__ entPS,
                              int2* __restrict__ entAP, int2* __restrict__ entSP,
                              int ePA, int ePS) {
    int i = blockIdx.x * 256 + threadIdx.x;
    const int *r, *c; const float* v; int* cur; int2* ent; int e;
    if (i < ePA) { e = i; r = pa_r; c = pa_c; v = pa_v; cur = curPA; ent = entPA; }
    else if (i < ePA + ePS) { e = i - ePA; r = ps_r; c = ps_c; v = ps_v; cur = curPS; ent = entPS; }
    else if (i < 2 * ePA + ePS) { e = i - ePA - ePS; r = ap_r; c = ap_c; v = ap_v; cur = curAP; ent = entAP; }
    else if (i < 2 * ePA + 2 * ePS) { e = i - 2 * ePA - ePS; r = sp_r; c = sp_c; v = sp_v; cur = curSP; ent = entSP; }
    else return;
    int rr = r[e];
    int pp = atomicAdd(&cur[rr], 1);
    ent[pp] = make_int2(c[e], __float_as_int(v[e]));
}

// ======================= row-parallel spmm, bf16 h =======================
__global__ __launch_bounds__(256)
void k_row1(unsigned short* __restrict__ dst, const unsigned short* __restrict__ y,
            const float* __restrict__ diag, const int* __restrict__ off,
            const int2* __restrict__ ent, const unsigned short* __restrict__ src, int n) {
    int r = (blockIdx.x * 256 + threadIdx.x) >> 6;
    int lane = threadIdx.x & 63;
    if (r >= n) return;
    float acc = diag[r] * bf2f(y[(size_t)r * 64 + lane]);
    int s = off[r], t = off[r + 1];
    int e = s;
    for (; e + 1 < t; e += 2) {
        int2 E0 = ent[e], E1 = ent[e + 1];
        acc += __int_as_float(E0.y) * bf2f(src[(size_t)E0.x * 64 + lane])
             + __int_as_float(E1.y) * bf2f(src[(size_t)E1.x * 64 + lane]);
    }
    if (e < t) {
        int2 E = ent[e];
        acc += __int_as_float(E.y) * bf2f(src[(size_t)E.x * 64 + lane]);
    }
    dst[(size_t)r * 64 + lane] = f2bf(acc);
}

// hP = 0.5*(dA+dB)*yP + 0.5*spmmA(srcA) + 0.5*spmmB(srcB)  [+ b2 -> fp32 out]
template<int FINAL>
__global__ __launch_bounds__(256)
void k_row2(unsigned short* __restrict__ dst, float* __restrict__ dstf,
            const unsigned short* __restrict__ yP,
            const float* __restrict__ dA, const float* __restrict__ dB,
            const int* __restrict__ offA, const int2* __restrict__ entA,
            const unsigned short* __restrict__ srcA,
            const int* __restrict__ offB, const int2* __restrict__ entB,
            const unsigned short* __restrict__ srcB,
            const float* __restrict__ b2, int n) {
    int r = (blockIdx.x * 256 + threadIdx.x) >> 6;
    int lane = threadIdx.x & 63;
    if (r >= n) return;
    float acc = (dA[r] + dB[r]) * bf2f(yP[(size_t)r * 64 + lane]);
    {
        int s = offA[r], t = offA[r + 1];
        int e = s;
        for (; e + 1 < t; e += 2) {
            int2 E0 = entA[e], E1 = entA[e + 1];
            acc += __int_as_float(E0.y) * bf2f(srcA[(size_t)E0.x * 64 + lane])
                 + __int_as_float(E1.y) * bf2f(srcA[(size_t)E1.x * 64 + lane]);
        }
        if (e < t) {
            int2 E = entA[e];
            acc += __int_as_float(E.y) * bf2f(srcA[(size_t)E.x * 64 + lane]);
        }
    }
    {
        int s = offB[r], t = offB[r + 1];
        int e = s;
        for (; e + 1 < t; e += 2) {
            int2 E0 = entB[e], E1 = entB[e + 1];
            acc += __int_as_float(E0.y) * bf2f(srcB[(size_t)E0.x * 64 + lane])
                 + __int_as_float(E1.y) * bf2f(srcB[(size_t)E1.x * 64 + lane]);
        }
        if (e < t) {
            int2 E = entB[e];
            acc += __int_as_float(E.y) * bf2f(srcB[(size_t)E.x * 64 + lane]);
        }
    }
    acc *= 0.5f;
    if (FINAL) dstf[(size_t)r * 64 + lane] = acc + b2[lane];
    else       dst[(size_t)r * 64 + lane] = f2bf(acc);
}

extern "C" void kernel_launch(void* const* d_in, const int* in_sizes, int n_in,
                              void* d_out, int out_size, void* d_ws, size_t ws_size,
                              hipStream_t stream) {
    const float* x_P = (const float*)d_in[0];
    const float* x_A = (const float*)d_in[1];
    const float* x_S = (const float*)d_in[2];
    const int* pa_row = (const int*)d_in[3];
    const int* pa_col = (const int*)d_in[4];
    const float* pa_val = (const float*)d_in[5];
    const int* ps_row = (const int*)d_in[6];
    const int* ps_col = (const int*)d_in[7];
    const float* ps_val = (const float*)d_in[8];
    const int* ap_row = (const int*)d_in[9];
    const int* ap_col = (const int*)d_in[10];
    const float* ap_val = (const float*)d_in[11];
    const int* sp_row = (const int*)d_in[12];
    const int* sp_col = (const int*)d_in[13];
    const float* sp_val = (const float*)d_in[14];
    const float* diag_PA = (const float*)d_in[15];
    const float* diag_PS = (const float*)d_in[16];
    const float* diag_AP = (const float*)d_in[17];
    const float* diag_SP = (const float*)d_in[18];
    const float* W1_P = (const float*)d_in[19];
    const float* b1_P = (const float*)d_in[20];
    const float* W1_A = (const float*)d_in[21];
    const float* b1_A = (const float*)d_in[22];
    const float* W1_S = (const float*)d_in[23];
    const float* b1_S = (const float*)d_in[24];
    const float* W2  = (const float*)d_in[25];
    const float* b2  = (const float*)d_in[26];

    const int nP = in_sizes[15], nA = in_sizes[17], nS = in_sizes[18];
    const int ePA = in_sizes[3], ePS = in_sizes[6];
    const int NC = 2 * nP + nA + nS;

    char* base = (char*)d_ws;
    size_t cur = 0;
    auto alloc = [&](size_t bytes) -> char* {
        cur = (cur + 255) & ~(size_t)255;
        char* p = base + cur;
        cur += bytes;
        return p;
    };
    unsigned short* yP = (unsigned short*)alloc((size_t)nP * 64 * 2);
    unsigned short* yA = (unsigned short*)alloc((size_t)nA * 64 * 2);
    unsigned short* yS = (unsigned short*)alloc((size_t)nS * 64 * 2);
    unsigned short* hP = (unsigned short*)alloc((size_t)nP * 64 * 2);
    unsigned short* hA = (unsigned short*)alloc((size_t)nA * 64 * 2);
    unsigned short* hS = (unsigned short*)alloc((size_t)nS * 64 * 2);
    unsigned short* Wpk = (unsigned short*)alloc(212992 * 2);
    int* cnt  = (int*)alloc((size_t)NC * 4);
    int* off0 = (int*)alloc((size_t)NC * 4);
    int* offPA = (int*)alloc((size_t)(nP + 1) * 4);
    int* offPS = (int*)alloc((size_t)(nP + 1) * 4);
    int* offAP = (int*)alloc((size_t)(nA + 1) * 4);
    int* offSP = (int*)alloc((size_t)(nS + 1) * 4);
    int* curPA = (int*)alloc((size_t)nP * 4);
    int* curPS = (int*)alloc((size_t)nP * 4);
    int* curAP = (int*)alloc((size_t)nA * 4);
    int* curSP = (int*)alloc((size_t)nS * 4);
    int2* entPA = (int2*)alloc((size_t)ePA * 8);
    int2* entPS = (int2*)alloc((size_t)ePS * 8);
    int2* entAP = (int2*)alloc((size_t)ePA * 8);
    int2* entSP = (int2*)alloc((size_t)ePS * 8);
    int* bsum = (int*)alloc(1024 * 4);
    (void)ws_size;

    // ---- weights pack + CSR build ----
    k_prep<<<(212992 + 255) / 256, 256, 0, stream>>>(W1_P, W1_A, W1_S, W2, Wpk);
    hipMemsetAsync(cnt, 0, (size_t)NC * 4, stream);
    const int eTot = 2 * (ePA + ePS);
    k_count_all<<<(eTot + 255) / 256, 256, 0, stream>>>(pa_row, ps_row, ap_row, sp_row,
                                                        cnt, nP, nA, ePA, ePS);
    const int nb = (NC + 1023) / 1024;
    k_scan1<<<nb, 256, 0, stream>>>(cnt, off0, bsum, NC);
    k_scan2<<<1, 256, 0, stream>>>(bsum, nb);
    k_scan3<<<(NC + 255) / 256, 256, 0, stream>>>(off0, bsum, offPA, offPS, offAP, offSP,
                                                  curPA, curPS, curAP, curSP,
                                                  nP, nA, nS, ePA, ePS);
    k_scatter_all<<<(eTot + 255) / 256, 256, 0, stream>>>(
        pa_row, pa_col, pa_val, ps_row, ps_col, ps_val,
        ap_row, ap_col, ap_val, sp_row, sp_col, sp_val,
        curPA, curPS, curAP, curSP, entPA, entPS, entAP, entSP, ePA, ePS);

    // ---- projections (single pipelined dispatch) ----
    k_proj_all<<<512, 256, 0, stream>>>(x_P, x_A, x_S, Wpk, b1_P, b1_A, b1_S,
                                        yP, yA, yS, nP, nA, nS);

    // ---- hops (hop-3 hA/hS dead -> skipped; b2 fused into final) ----
    const int gbP = (nP + 3) / 4, gbA = (nA + 3) / 4, gbS = (nS + 3) / 4;
    // hop 1
    k_row2<0><<<gbP, 256, 0, stream>>>(hP, nullptr, yP, diag_PA, diag_PS,
                                       offPA, entPA, yA, offPS, entPS, yS, b2, nP);
    k_row1<<<gbA, 256, 0, stream>>>(hA, yA, diag_AP, offAP, entAP, hP, nA);
    k_row1<<<gbS, 256, 0, stream>>>(hS, yS, diag_SP, offSP, entSP, hP, nS);
    // hop 2
    k_row2<0><<<gbP, 256, 0, stream>>>(hP, nullptr, yP, diag_PA, diag_PS,
                                       offPA, entPA, hA, offPS, entPS, hS, b2, nP);
    k_row1<<<gbA, 256, 0, stream>>>(hA, yA, diag_AP, offAP, entAP, hP, nA);
    k_row1<<<gbS, 256, 0, stream>>>(hS, yS, diag_SP, offSP, entSP, hP, nS);
    // hop 3: only hP needed; write fp32 + b2 straight to d_out
    k_row2<1><<<gbP, 256, 0, stream>>>(nullptr, (float*)d_out, yP, diag_PA, diag_PS,
                                       offPA, entPA, hA, offPS, entPS, hS, b2, nP);
}